// Round 5
// baseline (306.749 us; speedup 1.0000x reference)
//
#include <hip/hip_runtime.h>

#define B 8
#define N 2048
#define FIN 10
#define D 128
#define ALPHA 0.02f
#define BR 32      // rows per block, k_proj
#define TIA 16     // i-rows per k_attn block
#define NSTEP (N / 4 / 32)          // 16 k-steps of 32 j per wave
#define NBLK_ATTN ((N / TIA) * B)   // 1024

typedef short bf8 __attribute__((ext_vector_type(8)));   // 8 bf16 in 4 VGPRs
typedef float f32x4 __attribute__((ext_vector_type(4)));

__device__ __forceinline__ float lrelu(float x) { return x >= 0.f ? x : ALPHA * x; }

__device__ __forceinline__ short f2b(float f) {
    unsigned u = __float_as_uint(f);
    return (short)((u + 0x7fffu + ((u >> 16) & 1u)) >> 16);
}

__device__ __forceinline__ float b2f(short s) {
    return __uint_as_float(((unsigned)(unsigned short)s) << 16);
}

__device__ __forceinline__ unsigned enc_key(float v) {
    unsigned b = __float_as_uint(v);
    return (b & 0x80000000u) ? ~b : (b | 0x80000000u);
}
__device__ __forceinline__ float dec_key(unsigned k) {
    unsigned b = (k & 0x80000000u) ? (k & 0x7fffffffu) : ~k;
    return __uint_as_float(b);
}

// ---------------------------------------------------------------------------
// k_proj: x = lrelu(LN(h@W1^T+b1)) [bf16] ; Wh = x@Wg^T+bg via MFMA (fp32 acc);
// emits WhT bf16 [d][j] + e1,e2 fp32. Also zero-inits pooled + completion cnt.
// Block = 32 rows, 256 threads (4 waves). Grid = B*N/32 = 512.  (unchanged)
// ---------------------------------------------------------------------------
__global__ __launch_bounds__(256) void k_proj(
    const float* __restrict__ h, const float* __restrict__ W1, const float* __restrict__ b1,
    const float* __restrict__ Wg, const float* __restrict__ bg,
    const float* __restrict__ a1, const float* __restrict__ a2,
    unsigned short* __restrict__ WhT, float* __restrict__ e1g, float* __restrict__ e2g,
    unsigned* __restrict__ pooled, unsigned* __restrict__ cnt)
{
    __shared__ __align__(16) short xep_lds[32 * 136];
    __shared__ __align__(16) short wg_lds[D * 136];
    __shared__ float W1_lds[D * 11];
    __shared__ float h_lds[BR * FIN];
    __shared__ float ep1[2][BR], ep2[2][BR];

    const int t = threadIdx.x;
    const int r0 = blockIdx.x * BR;
    const int bb = r0 >> 11;
    const int jloc = r0 & (N - 1);

    // zero-init pooled (blocks 0..7) and counter (block 0)
    if (blockIdx.x < B && t < D) pooled[blockIdx.x * D + t] = 0u;
    if (blockIdx.x == 0 && t == 128) *cnt = 0u;

    for (int idx = t; idx < D * FIN; idx += 256)
        W1_lds[(idx / FIN) * 11 + (idx % FIN)] = W1[idx];
    for (int idx = t; idx < BR * FIN; idx += 256)
        h_lds[idx] = h[(size_t)r0 * FIN + idx];
    __syncthreads();

    // stage Wg -> bf16 LDS [dout][din]
    {
        const int dr = t >> 4;
        const int j8 = t & 15;
        #pragma unroll
        for (int pass = 0; pass < 8; pass++) {
            int dd = pass * 16 + dr;
            float4 f0 = *(const float4*)&Wg[dd * D + j8 * 8];
            float4 f1 = *(const float4*)&Wg[dd * D + j8 * 8 + 4];
            bf8 v;
            v[0] = f2b(f0.x); v[1] = f2b(f0.y); v[2] = f2b(f0.z); v[3] = f2b(f0.w);
            v[4] = f2b(f1.x); v[5] = f2b(f1.y); v[6] = f2b(f1.z); v[7] = f2b(f1.w);
            *(bf8*)&wg_lds[dd * 136 + j8 * 8] = v;
        }
    }

    // phase 1: fc1 + LN + lrelu, one row per wave iteration
    const int w = t >> 6, lane = t & 63;
    {
        float b1v0 = b1[lane], b1v1 = b1[lane + 64];
        for (int i = 0; i < 8; i++) {
            int r = w * 8 + i;
            float s0 = b1v0, s1 = b1v1;
            const float* hr = &h_lds[r * FIN];
            #pragma unroll
            for (int k = 0; k < FIN; k++) {
                float hv = hr[k];
                s0 += hv * W1_lds[lane * 11 + k];
                s1 += hv * W1_lds[(lane + 64) * 11 + k];
            }
            float sm = s0 + s1, sq = s0 * s0 + s1 * s1;
            #pragma unroll
            for (int m = 1; m <= 32; m <<= 1) { sm += __shfl_xor(sm, m); sq += __shfl_xor(sq, m); }
            float mean = sm * (1.f / D);
            float var  = sq * (1.f / D) - mean * mean;
            float rs = rsqrtf(var + 1e-5f);
            xep_lds[r * 136 + lane]      = f2b(lrelu((s0 - mean) * rs));
            xep_lds[r * 136 + lane + 64] = f2b(lrelu((s1 - mean) * rs));
        }
    }
    __syncthreads();

    // phase 2: MFMA  Wh[32][128] = x @ Wg^T
    const int l15 = lane & 15, q = lane >> 4;
    const int mw = w & 1, np = w >> 1;
    f32x4 acc[4];
    #pragma unroll
    for (int nt = 0; nt < 4; nt++)
        #pragma unroll
        for (int r = 0; r < 4; r++) acc[nt][r] = 0.f;

    #pragma unroll
    for (int ks = 0; ks < 4; ks++) {
        bf8 av = *(const bf8*)&xep_lds[(mw * 16 + l15) * 136 + ks * 32 + q * 8];
        #pragma unroll
        for (int nt = 0; nt < 4; nt++) {
            bf8 bv = *(const bf8*)&wg_lds[((np * 4 + nt) * 16 + l15) * 136 + ks * 32 + q * 8];
            acc[nt] = __builtin_amdgcn_mfma_f32_16x16x32_bf16(av, bv, acc[nt], 0, 0, 0);
        }
    }

    // epilogue: +bg, e1/e2 partials
    float e1p[4] = {0.f, 0.f, 0.f, 0.f}, e2p[4] = {0.f, 0.f, 0.f, 0.f};
    #pragma unroll
    for (int nt = 0; nt < 4; nt++) {
        int col = (np * 4 + nt) * 16 + l15;
        float bgv = bg[col], a1v = a1[col], a2v = a2[col];
        #pragma unroll
        for (int r = 0; r < 4; r++) {
            float v = acc[nt][r] + bgv;
            acc[nt][r] = v;
            e1p[r] += v * a1v;
            e2p[r] += v * a2v;
        }
    }
    #pragma unroll
    for (int m = 1; m <= 8; m <<= 1) {
        #pragma unroll
        for (int r = 0; r < 4; r++) { e1p[r] += __shfl_xor(e1p[r], m); e2p[r] += __shfl_xor(e2p[r], m); }
    }
    if (l15 == 0) {
        #pragma unroll
        for (int r = 0; r < 4; r++) {
            ep1[np][mw * 16 + q * 4 + r] = e1p[r];
            ep2[np][mw * 16 + q * 4 + r] = e2p[r];
        }
    }
    __syncthreads();
    if (t < BR) {
        e1g[r0 + t] = ep1[0][t] + ep1[1][t];
        e2g[r0 + t] = ep2[0][t] + ep2[1][t];
    }
    #pragma unroll
    for (int nt = 0; nt < 4; nt++) {
        int col = (np * 4 + nt) * 16 + l15;
        #pragma unroll
        for (int r = 0; r < 4; r++)
            xep_lds[col * 36 + mw * 16 + q * 4 + r] = f2b(acc[nt][r]);
    }
    __syncthreads();
    {
        const int col = t >> 1, jh = (t & 1) * 16;
        unsigned short* dst = WhT + ((size_t)(bb * D + col)) * N + jloc + jh;
        #pragma unroll
        for (int i2 = 0; i2 < 4; i2++)
            *(uint2*)(dst + i2 * 4) = *(const uint2*)&xep_lds[col * 36 + jh + i2 * 4];
    }
}

// ---------------------------------------------------------------------------
// k_attn v6 = v4 (wave-independent, ZERO main-loop barriers, harness-VERIFIED)
// + scheduling fences. v4's failure was pure scheduling: compiler sank the
// global prefetch loads to their uses (VGPR=64 proved it), serializing L2/L3
// latency per MFMA. Fix:
//  - ALL global loads (8 bv B-fragments + next-step adj/e2) issued at the
//    TOP of each step, then __builtin_amdgcn_sched_barrier(0): a hard fence
//    the scheduler cannot move loads across. The ~200cy exp chain + 4
//    blocks/CU TLP then covers the load latency.
//  - s_setprio(1/0) around the MFMA cluster (T5).
//  - launch_bounds(256,4) caps VGPR at 128 (need ~100).
// Diagnostic: VGPR_Count must jump 64 -> ~100+; if not, the fence failed.
// Block = 256 threads (4 waves). Grid = (N/16, B) = 1024 -> 4 blk/CU.
// ---------------------------------------------------------------------------
__global__ __launch_bounds__(256, 4) void k_attn(
    const int* __restrict__ adj, const unsigned short* __restrict__ WhT,
    const float* __restrict__ e1g, const float* __restrict__ e2g,
    unsigned* __restrict__ pooled, unsigned* __restrict__ cnt,
    const float* __restrict__ W2, const float* __restrict__ b2,
    float* __restrict__ out)
{
    __shared__ float obufp[4][TIA][132];   // per-wave O partials, pad to 132
    __shared__ float lp[4][TIA];           // per-wave row-sum partials
    __shared__ unsigned maxd[D];           // per-d max (enc_key)
    __shared__ int finalflag;

    const int t = threadIdx.x;
    const int b = blockIdx.y;
    const int i0 = blockIdx.x * TIA;
    const int w = t >> 6, lane = t & 63;
    const int l15 = lane & 15, q = lane >> 4;

    if (t < D) maxd[t] = 0u;

    const float e1v = e1g[b * N + i0 + l15];
    const float* e2b = e2g + (size_t)b * N;
    const int* adjr = adj + ((size_t)b * N + i0 + l15) * N;
    const unsigned short* wb = WhT + (size_t)b * D * N + (size_t)l15 * N + q * 8;

    f32x4 acc[8];
    #pragma unroll
    for (int nt = 0; nt < 8; nt++)
        #pragma unroll
        for (int r = 0; r < 4; r++) acc[nt][r] = 0.f;
    float ls = 0.f;

    const int jw0 = w * (N / 4);
    const int jq8 = q * 8;

    // prologue: adj/e2 for step 0
    int4 aa = *(const int4*)(adjr + jw0 + jq8);
    int4 ab = *(const int4*)(adjr + jw0 + jq8 + 4);
    float4 ea = *(const float4*)(e2b + jw0 + jq8);
    float4 eb = *(const float4*)(e2b + jw0 + jq8 + 4);

    for (int js = 0; js < NSTEP; js++) {
        const int jbase = jw0 + js * 32;
        const unsigned short* wbj = wb + jbase;

        // --- issue ALL of this step's global loads up front ---------------
        bf8 bv[8];
        #pragma unroll
        for (int nt = 0; nt < 8; nt++)
            bv[nt] = *(const bf8*)(wbj + (size_t)nt * 16 * N);

        // next step's adj/e2 into temporaries (current regs still needed)
        int4 na = aa, nb_ = ab;
        float4 nea = ea, neb = eb;
        if (js + 1 < NSTEP) {
            const int jn = jbase + 32;
            na  = *(const int4*)(adjr + jn + jq8);
            nb_ = *(const int4*)(adjr + jn + jq8 + 4);
            nea = *(const float4*)(e2b + jn + jq8);
            neb = *(const float4*)(e2b + jn + jq8 + 4);
        }
        // hard fence: no load may sink below this point
        __builtin_amdgcn_sched_barrier(0);

        // --- A-fragment: 8 in-lane P values (row l15, j = jbase + q*8 + e)
        // uses PREVIOUS iteration's aa/ab/ea/eb (landed long ago)
        bf8 av;
        av[0] = f2b(aa.x ? __expf(lrelu(e1v + ea.x)) : 0.f);
        av[1] = f2b(aa.y ? __expf(lrelu(e1v + ea.y)) : 0.f);
        av[2] = f2b(aa.z ? __expf(lrelu(e1v + ea.z)) : 0.f);
        av[3] = f2b(aa.w ? __expf(lrelu(e1v + ea.w)) : 0.f);
        av[4] = f2b(ab.x ? __expf(lrelu(e1v + eb.x)) : 0.f);
        av[5] = f2b(ab.y ? __expf(lrelu(e1v + eb.y)) : 0.f);
        av[6] = f2b(ab.z ? __expf(lrelu(e1v + eb.z)) : 0.f);
        av[7] = f2b(ab.w ? __expf(lrelu(e1v + eb.w)) : 0.f);
        ls += b2f(av[0]) + b2f(av[1]) + b2f(av[2]) + b2f(av[3])
            + b2f(av[4]) + b2f(av[5]) + b2f(av[6]) + b2f(av[7]);

        // --- MFMA cluster (bv vmcnt-waited here, ~exp-chain later) --------
        __builtin_amdgcn_s_setprio(1);
        #pragma unroll
        for (int nt = 0; nt < 8; nt++)
            acc[nt] = __builtin_amdgcn_mfma_f32_16x16x32_bf16(av, bv[nt], acc[nt], 0, 0, 0);
        __builtin_amdgcn_s_setprio(0);

        aa = na; ab = nb_; ea = nea; eb = neb;
    }

    // reduce row-sum across q groups (lanes l15, l15+16, +32, +48)
    ls += __shfl_xor(ls, 16);
    ls += __shfl_xor(ls, 32);
    if (lane < 16) lp[w][lane] = ls;

    // write O partials: acc[nt][r] = O[row = q*4+r][d = nt*16+l15]
    #pragma unroll
    for (int nt = 0; nt < 8; nt++)
        #pragma unroll
        for (int r = 0; r < 4; r++)
            obufp[w][q * 4 + r][nt * 16 + l15] = acc[nt][r];
    __syncthreads();

    // combine 4 partials; LN per row; lrelu; per-d max
    {
        const int ri = t >> 4;          // 0..15 row
        const int c  = t & 15;          // 16 threads per row
        const int dbase = c * 8;
        float lsum = lp[0][ri] + lp[1][ri] + lp[2][ri] + lp[3][ri];
        float rinv = 1.f / lsum;
        float o[8];
        #pragma unroll
        for (int k = 0; k < 8; k += 4) {
            float4 s0 = *(const float4*)&obufp[0][ri][dbase + k];
            float4 s1 = *(const float4*)&obufp[1][ri][dbase + k];
            float4 s2 = *(const float4*)&obufp[2][ri][dbase + k];
            float4 s3 = *(const float4*)&obufp[3][ri][dbase + k];
            o[k + 0] = (s0.x + s1.x + s2.x + s3.x) * rinv;
            o[k + 1] = (s0.y + s1.y + s2.y + s3.y) * rinv;
            o[k + 2] = (s0.z + s1.z + s2.z + s3.z) * rinv;
            o[k + 3] = (s0.w + s1.w + s2.w + s3.w) * rinv;
        }
        float sm = 0.f, sq = 0.f;
        #pragma unroll
        for (int k = 0; k < 8; k++) { sm += o[k]; sq += o[k] * o[k]; }
        #pragma unroll
        for (int m = 1; m <= 8; m <<= 1) { sm += __shfl_xor(sm, m); sq += __shfl_xor(sq, m); }
        float mean = sm * (1.f / D);
        float var  = sq * (1.f / D) - mean * mean;
        float rs = rsqrtf(var + 1e-5f);
        #pragma unroll
        for (int k = 0; k < 8; k++) {
            float v = lrelu((o[k] - mean) * rs);
            atomicMax(&maxd[dbase + k], enc_key(v));
        }
    }
    __syncthreads();
    if (t < D) atomicMax(&pooled[b * D + t], maxd[t]);
    __syncthreads();           // all this block's atomics drained

    // completion counter; last block does final 128->2 matmul + log_softmax
    if (t == 0) {
        __threadfence();
        unsigned old = atomicAdd(cnt, 1u);
        finalflag = (old == NBLK_ATTN - 1) ? 1 : 0;
    }
    __syncthreads();
    if (finalflag && t < 256) {
        const int fb = t >> 5;
        const int fq = t & 31;
        float s0 = 0.f, s1 = 0.f;
        #pragma unroll
        for (int m = 0; m < 4; m++) {
            int dd = fq + 32 * m;
            unsigned key = __hip_atomic_load(&pooled[fb * D + dd], __ATOMIC_RELAXED,
                                             __HIP_MEMORY_SCOPE_AGENT);
            float v = dec_key(key);
            s0 += v * W2[dd];
            s1 += v * W2[D + dd];
        }
        #pragma unroll
        for (int m = 1; m <= 16; m <<= 1) { s0 += __shfl_xor(s0, m); s1 += __shfl_xor(s1, m); }
        if (fq == 0) {
            float o0 = s0 + b2[0], o1 = s1 + b2[1];
            float mxv = fmaxf(o0, o1);
            float ls2 = logf(__expf(o0 - mxv) + __expf(o1 - mxv));
            out[fb * 2 + 0] = o0 - mxv - ls2;
            out[fb * 2 + 1] = o1 - mxv - ls2;
        }
    }
}

extern "C" void kernel_launch(void* const* d_in, const int* in_sizes, int n_in,
                              void* d_out, int out_size, void* d_ws, size_t ws_size,
                              hipStream_t stream) {
    const float* h   = (const float*)d_in[0];
    const int*   adj = (const int*)d_in[1];
    const float* W1  = (const float*)d_in[2];
    const float* b1  = (const float*)d_in[3];
    const float* Wg  = (const float*)d_in[4];
    const float* bg  = (const float*)d_in[5];
    const float* a1  = (const float*)d_in[6];
    const float* a2  = (const float*)d_in[7];
    const float* W2  = (const float*)d_in[8];
    const float* b2  = (const float*)d_in[9];
    float* out = (float*)d_out;

    unsigned short* WhT = (unsigned short*)d_ws;                       // B*D*N bf16
    float* e1g = (float*)((char*)d_ws + (size_t)B * D * N * 2);        // B*N f32
    float* e2g = e1g + (size_t)B * N;                                  // B*N f32
    unsigned* pooled = (unsigned*)(e2g + (size_t)B * N);               // B*D u32
    unsigned* cnt = pooled + (size_t)B * D;                            // 1 u32

    k_proj<<<(B * N) / BR, 256, 0, stream>>>(h, W1, b1, Wg, bg, a1, a2,
                                             WhT, e1g, e2g, pooled, cnt);
    k_attn<<<dim3(N / TIA, B), 256, 0, stream>>>(adj, WhT, e1g, e2g, pooled, cnt,
                                                 W2, b2, out);
}

// Round 7
// 235.006 us; speedup vs baseline: 1.3053x; 1.3053x over previous
//
#include <hip/hip_runtime.h>

#define B 8
#define N 2048
#define FIN 10
#define D 128
#define ALPHA 0.02f
#define BR 32     // rows per block, k_proj
#define TI 32     // rows per block, k_attn
#define JC 128    // j-chunk, k_attn
#define NCH (N / JC)               // 16 chunks
#define NBLK_ATTN ((N / TI) * B)   // 512

typedef short bf8 __attribute__((ext_vector_type(8)));   // 8 bf16 in 4 VGPRs
typedef float f32x4 __attribute__((ext_vector_type(4)));

__device__ __forceinline__ float lrelu(float x) { return x >= 0.f ? x : ALPHA * x; }

__device__ __forceinline__ short f2b(float f) {
    unsigned u = __float_as_uint(f);
    return (short)((u + 0x7fffu + ((u >> 16) & 1u)) >> 16);
}

__device__ __forceinline__ float b2f(short s) {
    return __uint_as_float(((unsigned)(unsigned short)s) << 16);
}

__device__ __forceinline__ unsigned enc_key(float v) {
    unsigned b = __float_as_uint(v);
    return (b & 0x80000000u) ? ~b : (b | 0x80000000u);
}
__device__ __forceinline__ float dec_key(unsigned k) {
    unsigned b = (k & 0x80000000u) ? (k & 0x7fffffffu) : ~k;
    return __uint_as_float(b);
}

// async global->LDS DMA: no destination register, cannot be "sunk to use"
// by the scheduler; ordered purely by counted vmcnt (T3/T4, m201-proven).
// LDS dest semantics (m104/m173): wave-uniform base + lane*size.
__device__ __forceinline__ void dma16(const void* g, void* l) {
    __builtin_amdgcn_global_load_lds(
        (const __attribute__((address_space(1))) void*)g,
        (__attribute__((address_space(3))) void*)l, 16, 0, 0);
}
__device__ __forceinline__ void dma4(const void* g, void* l) {
    __builtin_amdgcn_global_load_lds(
        (const __attribute__((address_space(1))) void*)g,
        (__attribute__((address_space(3))) void*)l, 4, 0, 0);
}

// ---------------------------------------------------------------------------
// k_proj: x = lrelu(LN(h@W1^T+b1)) [bf16] ; Wh = x@Wg^T+bg via MFMA (fp32 acc);
// emits WhT bf16 [d][j] + e1,e2 fp32. Also zero-inits pooled + completion cnt.
// Block = 32 rows, 256 threads (4 waves). Grid = B*N/32 = 512.  (unchanged)
// ---------------------------------------------------------------------------
__global__ __launch_bounds__(256) void k_proj(
    const float* __restrict__ h, const float* __restrict__ W1, const float* __restrict__ b1,
    const float* __restrict__ Wg, const float* __restrict__ bg,
    const float* __restrict__ a1, const float* __restrict__ a2,
    unsigned short* __restrict__ WhT, float* __restrict__ e1g, float* __restrict__ e2g,
    unsigned* __restrict__ pooled, unsigned* __restrict__ cnt)
{
    __shared__ __align__(16) short xep_lds[32 * 136];
    __shared__ __align__(16) short wg_lds[D * 136];
    __shared__ float W1_lds[D * 11];
    __shared__ float h_lds[BR * FIN];
    __shared__ float ep1[2][BR], ep2[2][BR];

    const int t = threadIdx.x;
    const int r0 = blockIdx.x * BR;
    const int bb = r0 >> 11;
    const int jloc = r0 & (N - 1);

    // zero-init pooled (blocks 0..7) and counter (block 0)
    if (blockIdx.x < B && t < D) pooled[blockIdx.x * D + t] = 0u;
    if (blockIdx.x == 0 && t == 128) *cnt = 0u;

    for (int idx = t; idx < D * FIN; idx += 256)
        W1_lds[(idx / FIN) * 11 + (idx % FIN)] = W1[idx];
    for (int idx = t; idx < BR * FIN; idx += 256)
        h_lds[idx] = h[(size_t)r0 * FIN + idx];
    __syncthreads();

    // stage Wg -> bf16 LDS [dout][din]
    {
        const int dr = t >> 4;
        const int j8 = t & 15;
        #pragma unroll
        for (int pass = 0; pass < 8; pass++) {
            int dd = pass * 16 + dr;
            float4 f0 = *(const float4*)&Wg[dd * D + j8 * 8];
            float4 f1 = *(const float4*)&Wg[dd * D + j8 * 8 + 4];
            bf8 v;
            v[0] = f2b(f0.x); v[1] = f2b(f0.y); v[2] = f2b(f0.z); v[3] = f2b(f0.w);
            v[4] = f2b(f1.x); v[5] = f2b(f1.y); v[6] = f2b(f1.z); v[7] = f2b(f1.w);
            *(bf8*)&wg_lds[dd * 136 + j8 * 8] = v;
        }
    }

    // phase 1: fc1 + LN + lrelu, one row per wave iteration
    const int w = t >> 6, lane = t & 63;
    {
        float b1v0 = b1[lane], b1v1 = b1[lane + 64];
        for (int i = 0; i < 8; i++) {
            int r = w * 8 + i;
            float s0 = b1v0, s1 = b1v1;
            const float* hr = &h_lds[r * FIN];
            #pragma unroll
            for (int k = 0; k < FIN; k++) {
                float hv = hr[k];
                s0 += hv * W1_lds[lane * 11 + k];
                s1 += hv * W1_lds[(lane + 64) * 11 + k];
            }
            float sm = s0 + s1, sq = s0 * s0 + s1 * s1;
            #pragma unroll
            for (int m = 1; m <= 32; m <<= 1) { sm += __shfl_xor(sm, m); sq += __shfl_xor(sq, m); }
            float mean = sm * (1.f / D);
            float var  = sq * (1.f / D) - mean * mean;
            float rs = rsqrtf(var + 1e-5f);
            xep_lds[r * 136 + lane]      = f2b(lrelu((s0 - mean) * rs));
            xep_lds[r * 136 + lane + 64] = f2b(lrelu((s1 - mean) * rs));
        }
    }
    __syncthreads();

    // phase 2: MFMA  Wh[32][128] = x @ Wg^T
    const int l15 = lane & 15, q = lane >> 4;
    const int mw = w & 1, np = w >> 1;
    f32x4 acc[4];
    #pragma unroll
    for (int nt = 0; nt < 4; nt++)
        #pragma unroll
        for (int r = 0; r < 4; r++) acc[nt][r] = 0.f;

    #pragma unroll
    for (int ks = 0; ks < 4; ks++) {
        bf8 av = *(const bf8*)&xep_lds[(mw * 16 + l15) * 136 + ks * 32 + q * 8];
        #pragma unroll
        for (int nt = 0; nt < 4; nt++) {
            bf8 bv = *(const bf8*)&wg_lds[((np * 4 + nt) * 16 + l15) * 136 + ks * 32 + q * 8];
            acc[nt] = __builtin_amdgcn_mfma_f32_16x16x32_bf16(av, bv, acc[nt], 0, 0, 0);
        }
    }

    // epilogue: +bg, e1/e2 partials
    float e1p[4] = {0.f, 0.f, 0.f, 0.f}, e2p[4] = {0.f, 0.f, 0.f, 0.f};
    #pragma unroll
    for (int nt = 0; nt < 4; nt++) {
        int col = (np * 4 + nt) * 16 + l15;
        float bgv = bg[col], a1v = a1[col], a2v = a2[col];
        #pragma unroll
        for (int r = 0; r < 4; r++) {
            float v = acc[nt][r] + bgv;
            acc[nt][r] = v;
            e1p[r] += v * a1v;
            e2p[r] += v * a2v;
        }
    }
    #pragma unroll
    for (int m = 1; m <= 8; m <<= 1) {
        #pragma unroll
        for (int r = 0; r < 4; r++) { e1p[r] += __shfl_xor(e1p[r], m); e2p[r] += __shfl_xor(e2p[r], m); }
    }
    if (l15 == 0) {
        #pragma unroll
        for (int r = 0; r < 4; r++) {
            ep1[np][mw * 16 + q * 4 + r] = e1p[r];
            ep2[np][mw * 16 + q * 4 + r] = e2p[r];
        }
    }
    __syncthreads();
    if (t < BR) {
        e1g[r0 + t] = ep1[0][t] + ep1[1][t];
        e2g[r0 + t] = ep2[0][t] + ep2[1][t];
    }
    #pragma unroll
    for (int nt = 0; nt < 4; nt++) {
        int col = (np * 4 + nt) * 16 + l15;
        #pragma unroll
        for (int r = 0; r < 4; r++)
            xep_lds[col * 36 + mw * 16 + q * 4 + r] = f2b(acc[nt][r]);
    }
    __syncthreads();
    {
        const int col = t >> 1, jh = (t & 1) * 16;
        unsigned short* dst = WhT + ((size_t)(bb * D + col)) * N + jloc + jh;
        #pragma unroll
        for (int i2 = 0; i2 < 4; i2++)
            *(uint2*)(dst + i2 * 4) = *(const uint2*)&xep_lds[col * 36 + jh + i2 * 4];
    }
}

// ---------------------------------------------------------------------------
// k_attn v7b (= v7 + sched_barrier hygiene): all staging via global_load_lds
// DMA; counted vmcnt only; NO vmcnt(0) in the loop; 2 lgkm-only barriers per
// chunk. Per chunk, per wave, EXACTLY 8 DMA ops issued at the top:
//   [whT(c) x4] [adj(c+1) x2] [e2(c+1) x2]
// Waits: vmcnt(8) before phase A (adj/e2(c), issued a full chunk ago);
// vmcnt(4)+lgkmcnt(0)+barrier before MFMA (whT(c), issued at chunk top).
// whT LDS linear (DMA requires it); bank conflicts fixed by bijective XOR
// swizzle byte^=(row&7)<<4 on BOTH pre-swizzled global source and MFMA read
// (rule #21). adj/e2 double-buffered; phase-A map == staging map (each wave
// reads only rows it staged -> its own vmcnt guards the read).
// LDS = 77.4 KB -> 2 blocks/CU; grid 512 fully resident.
// Block = 32 i-rows, 512 threads (8 waves). Grid = (64, 8).
// ---------------------------------------------------------------------------
__global__ __launch_bounds__(512, 4) void k_attn(
    const int* __restrict__ adj, const unsigned short* __restrict__ WhT,
    const float* __restrict__ e1g, const float* __restrict__ e2g,
    unsigned* __restrict__ pooled, unsigned* __restrict__ cnt,
    const float* __restrict__ W2, const float* __restrict__ b2,
    float* __restrict__ out)
{
    __shared__ __align__(16) short whTL[D * JC];        // 32 KB, swizzled linear
    __shared__ __align__(16) int   adjL[2][TI * JC];    // 2 x 16 KB
    __shared__ __align__(16) float e2L[2][JC];          // 2 x 512 B
    __shared__ __align__(16) short pT[TI * 136];        // 8.7 KB (padded; ds_write)
    __shared__ float statsp[4][TI][2];
    __shared__ float maxb[2][D];
    __shared__ float l_lds[TI];
    __shared__ int finalflag;

    const int t = threadIdx.x;
    const int b = blockIdx.y;
    const int i0 = blockIdx.x * TI;

    const int w = t >> 6, lane = t & 63;
    const int l15 = lane & 15, q = lane >> 4;
    const int mw = w & 1;          // m-tile (0/1)
    const int np = w >> 1;         // n-quarter (0..3)

    // phase-A map: wave w owns rows {2w, 2w+1, 2w+16, 2w+17} (= rows it staged)
    const int sel = lane >> 4;            // 0..3
    const int c16 = lane & 15;            // 16 lanes per row, 8 cols each
    const int row_a = 2 * w + ((sel >> 1) << 4) + (sel & 1);

    const float e1row = e1g[b * N + i0 + row_a];
    const unsigned short* WhTb = WhT + (size_t)b * D * N;
    const int* adjb = adj + ((size_t)b * N + i0) * N;
    const float* e2b = e2g + (size_t)b * N;

    f32x4 acc[2];
    #pragma unroll
    for (int nt = 0; nt < 2; nt++)
        #pragma unroll
        for (int r = 0; r < 4; r++) acc[nt][r] = 0.f;
    float ls = 0.f;

    // ---- DMA staging helpers (issue order is program order) ----------------
    // whT chunk jc -> whTL (linear dest, source pre-swizzled): 4 ops/wave
    auto stage_whT = [&](int jc) {
        #pragma unroll
        for (int p = 0; p < 4; p++) {
            int x = p * 8192 + w * 1024 + lane * 16;   // linear dest byte
            int rowx = x >> 8;                          // 256 B per d-row
            int scol = (x & 255) ^ ((rowx & 7) << 4);   // pre-swizzled source col
            dma16((const char*)WhTb + (size_t)rowx * (N * 2) + jc * (JC * 2) + scol,
                  (char*)whTL + x);
        }
    };
    // adj chunk jcn -> adjL[buf]: 2 ops/wave (wave w stages rows 2w,2w+1,2w+16,2w+17)
    auto stage_adj = [&](int jcn, int buf) {
        #pragma unroll
        for (int p = 0; p < 2; p++) {
            int y = p * 8192 + w * 1024 + lane * 16;   // linear dest byte
            int rowy = y >> 9;                          // 512 B per i-row
            dma16((const char*)adjb + (size_t)rowy * (N * 4) + jcn * (JC * 4) + (y & 511),
                  (char*)&adjL[buf][0] + y);
        }
    };
    // e2 chunk jcn -> e2L[buf]: 2 ops/wave (all waves redundant, same data)
    auto stage_e2 = [&](int jcn, int buf) {
        dma4((const char*)e2b + jcn * (JC * 4) + lane * 4,
             (char*)&e2L[buf][0] + lane * 4);
        dma4((const char*)e2b + jcn * (JC * 4) + 256 + lane * 4,
             (char*)&e2L[buf][0] + 256 + lane * 4);
    };

    // prologue: adj(0)/e2(0) -> buffers 0   (4 ops outstanding)
    stage_adj(0, 0);
    stage_e2(0, 0);

    for (int jc = 0; jc < NCH; jc++) {
        const int cb = jc & 1;
        const int jn = (jc + 1) & (NCH - 1);   // wrap on last iter (harmless)

        // issue this chunk's 8 DMA ops: whT(c) x4, adj(c+1) x2, e2(c+1) x2
        stage_whT(jc);
        stage_adj(jn, cb ^ 1);
        stage_e2(jn, cb ^ 1);

        // adj(c)/e2(c) ready: 8 newer ops outstanding after them
        asm volatile("s_waitcnt vmcnt(8)" ::: "memory");
        __builtin_amdgcn_sched_barrier(0);

        // phase A: LDS adj/e2 -> exp -> pT (bf16), f32 row-sum
        {
            const char* abase = (char*)&adjL[cb][0]
                + ((sel >> 1) << 13) + w * 1024 + ((sel & 1) << 9) + c16 * 32;
            int4 av0 = *(const int4*)abase;
            int4 av1 = *(const int4*)(abase + 16);
            const char* ebase = (char*)&e2L[cb][0] + c16 * 32;
            float4 ev0 = *(const float4*)ebase;
            float4 ev1 = *(const float4*)(ebase + 16);
            bf8 pv;
            pv[0] = f2b(av0.x ? __expf(lrelu(e1row + ev0.x)) : 0.f);
            pv[1] = f2b(av0.y ? __expf(lrelu(e1row + ev0.y)) : 0.f);
            pv[2] = f2b(av0.z ? __expf(lrelu(e1row + ev0.z)) : 0.f);
            pv[3] = f2b(av0.w ? __expf(lrelu(e1row + ev0.w)) : 0.f);
            pv[4] = f2b(av1.x ? __expf(lrelu(e1row + ev1.x)) : 0.f);
            pv[5] = f2b(av1.y ? __expf(lrelu(e1row + ev1.y)) : 0.f);
            pv[6] = f2b(av1.z ? __expf(lrelu(e1row + ev1.z)) : 0.f);
            pv[7] = f2b(av1.w ? __expf(lrelu(e1row + ev1.w)) : 0.f);
            ls += b2f(pv[0]) + b2f(pv[1]) + b2f(pv[2]) + b2f(pv[3])
                + b2f(pv[4]) + b2f(pv[5]) + b2f(pv[6]) + b2f(pv[7]);
            *(bf8*)&pT[row_a * 136 + c16 * 8] = pv;
        }

        // whT(c) landed (4 newer: adj/e2 of c+1); pT writes done; rendezvous
        asm volatile("s_waitcnt vmcnt(4) lgkmcnt(0)" ::: "memory");
        __builtin_amdgcn_sched_barrier(0);
        __builtin_amdgcn_s_barrier();

        // MFMA: O[32][128] += P @ WhT^T  (swizzled whT reads)
        __builtin_amdgcn_s_setprio(1);
        #pragma unroll
        for (int ks = 0; ks < 4; ks++) {
            bf8 av = *(const bf8*)&pT[(mw * 16 + l15) * 136 + ks * 32 + q * 8];
            #pragma unroll
            for (int nt = 0; nt < 2; nt++) {
                int rowb = (np * 2 + nt) * 16 + l15;
                const bf8* bp = (const bf8*)((char*)whTL + rowb * 256
                                  + (((ks * 64 + q * 16) ^ ((l15 & 7) << 4))));
                acc[nt] = __builtin_amdgcn_mfma_f32_16x16x32_bf16(av, *bp, acc[nt], 0, 0, 0);
            }
        }
        __builtin_amdgcn_s_setprio(0);

        // readers done -> next chunk may overwrite pT/whTL (DMA issued after)
        asm volatile("s_waitcnt lgkmcnt(0)" ::: "memory");
        __builtin_amdgcn_sched_barrier(0);
        __builtin_amdgcn_s_barrier();
    }
    asm volatile("s_waitcnt vmcnt(0)" ::: "memory");   // drain wrap loads

    // row-sum reduce within each 16-lane row group; publish
    #pragma unroll
    for (int m = 1; m <= 8; m <<= 1) ls += __shfl_xor(ls, m);
    if (c16 == 0) l_lds[row_a] = ls;
    __syncthreads();

    // epilogue: /l -> LN stats (cross-np via LDS) -> lrelu -> max-pool
    float smr[4] = {0.f, 0.f, 0.f, 0.f}, sqr[4] = {0.f, 0.f, 0.f, 0.f};
    #pragma unroll
    for (int r = 0; r < 4; r++) {
        float rinv = 1.f / l_lds[mw * 16 + q * 4 + r];
        #pragma unroll
        for (int nt = 0; nt < 2; nt++) {
            float v = acc[nt][r] * rinv;
            acc[nt][r] = v;
            smr[r] += v;
            sqr[r] += v * v;
        }
    }
    #pragma unroll
    for (int m = 1; m <= 8; m <<= 1) {
        #pragma unroll
        for (int r = 0; r < 4; r++) { smr[r] += __shfl_xor(smr[r], m); sqr[r] += __shfl_xor(sqr[r], m); }
    }
    if (l15 == 0) {
        #pragma unroll
        for (int r = 0; r < 4; r++) {
            statsp[np][mw * 16 + q * 4 + r][0] = smr[r];
            statsp[np][mw * 16 + q * 4 + r][1] = sqr[r];
        }
    }
    __syncthreads();

    float mx[2] = {-1e30f, -1e30f};
    #pragma unroll
    for (int r = 0; r < 4; r++) {
        int row = mw * 16 + q * 4 + r;
        float s0 = statsp[0][row][0] + statsp[1][row][0] + statsp[2][row][0] + statsp[3][row][0];
        float s1 = statsp[0][row][1] + statsp[1][row][1] + statsp[2][row][1] + statsp[3][row][1];
        float mean = s0 * (1.f / D);
        float var  = s1 * (1.f / D) - mean * mean;
        float rs = rsqrtf(var + 1e-5f);
        #pragma unroll
        for (int nt = 0; nt < 2; nt++) {
            float v = lrelu((acc[nt][r] - mean) * rs);
            mx[nt] = fmaxf(mx[nt], v);
        }
    }
    #pragma unroll
    for (int m = 16; m <= 32; m <<= 1) {
        #pragma unroll
        for (int nt = 0; nt < 2; nt++) mx[nt] = fmaxf(mx[nt], __shfl_xor(mx[nt], m));
    }
    if (q == 0) {
        #pragma unroll
        for (int nt = 0; nt < 2; nt++) maxb[mw][(np * 2 + nt) * 16 + l15] = mx[nt];
    }
    __syncthreads();
    if (t < D) {
        float v = fmaxf(maxb[0][t], maxb[1][t]);
        atomicMax(&pooled[b * D + t], enc_key(v));
    }
    __syncthreads();           // all this block's atomics drained

    // completion counter; last block does final 128->2 matmul + log_softmax
    if (t == 0) {
        __threadfence();
        unsigned old = atomicAdd(cnt, 1u);
        finalflag = (old == NBLK_ATTN - 1) ? 1 : 0;
    }
    __syncthreads();
    if (finalflag && t < 256) {
        const int fb = t >> 5;
        const int fq = t & 31;
        float s0 = 0.f, s1 = 0.f;
        #pragma unroll
        for (int m = 0; m < 4; m++) {
            int dd = fq + 32 * m;
            unsigned key = __hip_atomic_load(&pooled[fb * D + dd], __ATOMIC_RELAXED,
                                             __HIP_MEMORY_SCOPE_AGENT);
            float v = dec_key(key);
            s0 += v * W2[dd];
            s1 += v * W2[D + dd];
        }
        #pragma unroll
        for (int m = 1; m <= 16; m <<= 1) { s0 += __shfl_xor(s0, m); s1 += __shfl_xor(s1, m); }
        if (fq == 0) {
            float o0 = s0 + b2[0], o1 = s1 + b2[1];
            float mxv = fmaxf(o0, o1);
            float ls2 = logf(__expf(o0 - mxv) + __expf(o1 - mxv));
            out[fb * 2 + 0] = o0 - mxv - ls2;
            out[fb * 2 + 1] = o1 - mxv - ls2;
        }
    }
}

extern "C" void kernel_launch(void* const* d_in, const int* in_sizes, int n_in,
                              void* d_out, int out_size, void* d_ws, size_t ws_size,
                              hipStream_t stream) {
    const float* h   = (const float*)d_in[0];
    const int*   adj = (const int*)d_in[1];
    const float* W1  = (const float*)d_in[2];
    const float* b1  = (const float*)d_in[3];
    const float* Wg  = (const float*)d_in[4];
    const float* bg  = (const float*)d_in[5];
    const float* a1  = (const float*)d_in[6];
    const float* a2  = (const float*)d_in[7];
    const float* W2  = (const float*)d_in[8];
    const float* b2  = (const float*)d_in[9];
    float* out = (float*)d_out;

    unsigned short* WhT = (unsigned short*)d_ws;                       // B*D*N bf16
    float* e1g = (float*)((char*)d_ws + (size_t)B * D * N * 2);        // B*N f32
    float* e2g = e1g + (size_t)B * N;                                  // B*N f32
    unsigned* pooled = (unsigned*)(e2g + (size_t)B * N);               // B*D u32
    unsigned* cnt = pooled + (size_t)B * D;                            // 1 u32

    k_proj<<<(B * N) / BR, 256, 0, stream>>>(h, W1, b1, Wg, bg, a1, a2,
                                             WhT, e1g, e2g, pooled, cnt);
    k_attn<<<dim3(N / TI, B), 512, 0, stream>>>(adj, WhT, e1g, e2g, pooled, cnt,
                                                W2, b2, out);
}